// Round 10
// baseline (198.958 us; speedup 1.0000x reference)
//
#include <hip/hip_runtime.h>

// Problem constants
constexpr int N  = 50000;    // nodes
constexpr int E  = 1600000;  // edges
constexpr int CH = 128;      // channels

// Bucket slab parameters
constexpr int BSZ  = 64;                   // nodes per bucket
constexpr int NB   = (N + BSZ - 1) / BSZ;  // 782 buckets
constexpr int CAP  = 2560;                 // slab capacity (mean 2046, +11 sigma)
constexpr int PBLK = 512;                  // scatter partition blocks (R10: 256->512, critical path /2)
constexpr int EPB  = E / PBLK;             // 3125 edges per partition block (exact)
constexpr int GEMM_BLOCKS = N / 16;        // 3125

// Workspace layout (bytes, 256-aligned)
constexpr size_t H_OFF     = 0;                        // h bf16 [N*CH]
constexpr size_t H_SZ      = (size_t)N * CH * 2;       // 12,800,000
constexpr size_t PAIRS_OFF = H_OFF + H_SZ;             // slabs [NB][CAP] u32 packed
constexpr size_t PAIRS_SZ  = (size_t)NB * CAP * 4;     // 8,007,680
constexpr size_t GCUR_OFF  = PAIRS_OFF + PAIRS_SZ;     // bump cursors [NB] i32
constexpr size_t GCUR_SZ   = 3328;
constexpr size_t REQUIRED  = GCUR_OFF + GCUR_SZ;       // ~20.8 MB
constexpr size_t FB_REQUIRED = H_SZ;                   // fallback: h only

// float -> bf16 round-to-nearest-even (finite inputs)
static __device__ __forceinline__ ushort f2bf(float f) {
    unsigned u = __float_as_uint(f);
    return (ushort)((u + 0x7fffu + ((u >> 16) & 1u)) >> 16);
}
static __device__ __forceinline__ float bf_lo(unsigned u) { return __uint_as_float(u << 16); }
static __device__ __forceinline__ float bf_hi(unsigned u) { return __uint_as_float(u & 0xffff0000u); }

typedef __attribute__((ext_vector_type(8))) short bf16x8;
typedef __attribute__((ext_vector_type(4))) float f32x4;

// ---------------- GEMM body: 16 rows x 128 cols per 256-thread block ----------------
// mfma_f32_16x16x32_bf16, verified layouts (m89/m91): A[m=lane&15][k=q*8+j],
// B[n=lane&15][k=q*8+j], D col=lane&15,row=q*4+reg. W converted in-register.
static __device__ __forceinline__ void gemm_body(int gb, int tid,
                                                 const float* __restrict__ x,
                                                 const float* __restrict__ W,
                                                 const float* __restrict__ bias,
                                                 ushort* __restrict__ h) {
    const int m    = tid & 15;
    const int q    = (tid >> 4) & 3;
    const int wave = tid >> 6;
    const int r0   = gb * 16;
    const int c0   = wave * 32;

    const float* xrow = x + (size_t)(r0 + m) * CH + q * 8;
    const float* wr0  = W + (size_t)(c0 + m) * CH + q * 8;
    const float* wr1  = wr0 + 16 * CH;

    f32x4 acc0 = {0.f, 0.f, 0.f, 0.f};
    f32x4 acc1 = {0.f, 0.f, 0.f, 0.f};

#pragma unroll
    for (int kc = 0; kc < CH; kc += 32) {
        float4 xa = *(const float4*)(xrow + kc);
        float4 xb = *(const float4*)(xrow + kc + 4);
        float4 wa0 = *(const float4*)(wr0 + kc);
        float4 wb0 = *(const float4*)(wr0 + kc + 4);
        float4 wa1 = *(const float4*)(wr1 + kc);
        float4 wb1 = *(const float4*)(wr1 + kc + 4);
        bf16x8 a, b0, b1;
        a[0] = (short)f2bf(xa.x); a[1] = (short)f2bf(xa.y);
        a[2] = (short)f2bf(xa.z); a[3] = (short)f2bf(xa.w);
        a[4] = (short)f2bf(xb.x); a[5] = (short)f2bf(xb.y);
        a[6] = (short)f2bf(xb.z); a[7] = (short)f2bf(xb.w);
        b0[0] = (short)f2bf(wa0.x); b0[1] = (short)f2bf(wa0.y);
        b0[2] = (short)f2bf(wa0.z); b0[3] = (short)f2bf(wa0.w);
        b0[4] = (short)f2bf(wb0.x); b0[5] = (short)f2bf(wb0.y);
        b0[6] = (short)f2bf(wb0.z); b0[7] = (short)f2bf(wb0.w);
        b1[0] = (short)f2bf(wa1.x); b1[1] = (short)f2bf(wa1.y);
        b1[2] = (short)f2bf(wa1.z); b1[3] = (short)f2bf(wa1.w);
        b1[4] = (short)f2bf(wb1.x); b1[5] = (short)f2bf(wb1.y);
        b1[6] = (short)f2bf(wb1.z); b1[7] = (short)f2bf(wb1.w);
        acc0 = __builtin_amdgcn_mfma_f32_16x16x32_bf16(a, b0, acc0, 0, 0, 0);
        acc1 = __builtin_amdgcn_mfma_f32_16x16x32_bf16(a, b1, acc1, 0, 0, 0);
    }

    const int col0 = c0 + m;
    const float bb0 = bias[col0];
    const float bb1 = bias[col0 + 16];
#pragma unroll
    for (int r = 0; r < 4; r++) {
        size_t row = (size_t)(r0 + q * 4 + r) * CH;
        h[row + col0]      = f2bf(acc0[r] + bb0);
        h[row + col0 + 16] = f2bf(acc1[r] + bb1);
    }
}

// ---------------- fused: edge scatter (blocks 0..PBLK) | GEMM (rest) ----------------
// Scatter role: LDS int histogram of this block's 3125 edges by bucket, ONE
// global atomicAdd per non-empty bucket to bump-reserve a contiguous range in
// the bucket's slab (no scans), then re-read edges (L2-hot) and write packed
// (dstLoc<<16 | src) via LDS cursors. Scatter blocks lead the grid so their
// latency hides under the GEMM blocks. gcur must be pre-zeroed.
__global__ __launch_bounds__(256) void gemm_and_scatter(const float* __restrict__ x,
                                                        const float* __restrict__ W,
                                                        const float* __restrict__ bias,
                                                        ushort* __restrict__ h,
                                                        const int* __restrict__ ei,
                                                        int* __restrict__ gcur,
                                                        unsigned* __restrict__ pairs) {
    __shared__ int cnt[NB];
    __shared__ int cur[NB];
    const int bid = blockIdx.x;
    const int tid = threadIdx.x;

    if (bid >= PBLK) {
        gemm_body(bid - PBLK, tid, x, W, bias, h);
        return;
    }

    const int k = bid;
    for (int j = tid; j < NB; j += 256) cnt[j] = 0;
    __syncthreads();
    const int* dp = ei + k * EPB;
    const int* sp = ei + E + k * EPB;
    for (int i = tid; i < EPB; i += 256) atomicAdd(&cnt[dp[i] >> 6], 1);
    __syncthreads();
    for (int j = tid; j < NB; j += 256) {
        int c = cnt[j];
        cur[j] = j * CAP + (c ? atomicAdd(&gcur[j], c) : 0);
    }
    __syncthreads();
    for (int i = tid; i < EPB; i += 256) {
        int d = dp[i], s = sp[i];
        int bb = d >> 6;
        int p = atomicAdd(&cur[bb], 1);
        if (p < (bb + 1) * CAP)              // defensive: never corrupt a neighbor slab
            pairs[p] = ((unsigned)(d & (BSZ - 1)) << 16) | (unsigned)s;
    }
}

// ---------------- fused local-CSR build + pull aggregation (1 bucket / block) ----------------
// 8 waves. Stage the bucket slab to LDS, int-atomic hist over 64 nodes, ladder
// scan, scatter src16 into srt[] (CSR entirely in LDS). Aggregation: each wave
// owns 8 nodes; QUARTER-wave (16 lanes) per edge, lane reads uint4 = 8 bf16
// channels (16 B: coalescing sweet spot). One vmem instr covers 4 rows; x4
// unroll => 16 rows in flight per wave. srt reads are quarter-broadcast (free).
// Reduce across quarters with shfl_xor(16|32); lanes 0..15 store 2x float4.
__global__ __launch_bounds__(512) void agg_fused(const ushort* __restrict__ h,
                                                 const unsigned* __restrict__ pairs,
                                                 const int* __restrict__ gcur,
                                                 float* __restrict__ out) {
    __shared__ unsigned raw[CAP];        // 10240 B
    __shared__ ushort   srt[CAP];        //  5120 B
    __shared__ int hist[BSZ], offs[BSZ], cur[BSZ];
    const int b = blockIdx.x, t = threadIdx.x;
    const int cnt = min(gcur[b], CAP);
    const int wave = t >> 6;
    const int lane = t & 63;
    const int quarter = lane >> 4;       // 0..3: which edge of a 4-edge group
    const int cq      = lane & 15;       // channel octet 0..15 (8 ch each)

    const unsigned* slab = pairs + (size_t)b * CAP;
    for (int i = t; i < cnt; i += 512) raw[i] = slab[i];
    if (t < BSZ) hist[t] = 0;
    __syncthreads();
    for (int i = t; i < cnt; i += 512) atomicAdd(&hist[raw[i] >> 16], 1);
    __syncthreads();
    int v = (t < BSZ) ? hist[t] : 0;
    if (t < BSZ) offs[t] = v;
    __syncthreads();
    for (int o = 1; o < BSZ; o <<= 1) {
        int u = 0;
        if (t < BSZ && t >= o) u = offs[t - o];
        __syncthreads();
        if (t < BSZ) offs[t] += u;
        __syncthreads();
    }
    if (t < BSZ) { int excl = offs[t] - v; offs[t] = excl; cur[t] = excl; }
    __syncthreads();
    for (int i = t; i < cnt; i += 512) {
        unsigned w = raw[i];
        int p = atomicAdd(&cur[w >> 16], 1);
        srt[p] = (ushort)(w & 0xffffu);
    }
    __syncthreads();

    const ushort* hp = h + (size_t)cq * 8;   // this lane's 8 channels

#pragma unroll
    for (int j = 0; j < 8; j++) {
        const int nl = wave * 8 + j;
        const int st = offs[nl];
        const int c  = hist[nl];
        float a0 = 0.f, a1 = 0.f, a2 = 0.f, a3 = 0.f;
        float a4 = 0.f, a5 = 0.f, a6 = 0.f, a7 = 0.f;
        int i = 0;
        for (; i + 16 <= c; i += 16) {
            const int e0 = st + i + quarter;
            int s0 = srt[e0];
            int s1 = srt[e0 + 4];
            int s2 = srt[e0 + 8];
            int s3 = srt[e0 + 12];
            uint4 v0 = *(const uint4*)(hp + (size_t)s0 * CH);
            uint4 v1 = *(const uint4*)(hp + (size_t)s1 * CH);
            uint4 v2 = *(const uint4*)(hp + (size_t)s2 * CH);
            uint4 v3 = *(const uint4*)(hp + (size_t)s3 * CH);
            a0 += bf_lo(v0.x); a1 += bf_hi(v0.x); a2 += bf_lo(v0.y); a3 += bf_hi(v0.y);
            a4 += bf_lo(v0.z); a5 += bf_hi(v0.z); a6 += bf_lo(v0.w); a7 += bf_hi(v0.w);
            a0 += bf_lo(v1.x); a1 += bf_hi(v1.x); a2 += bf_lo(v1.y); a3 += bf_hi(v1.y);
            a4 += bf_lo(v1.z); a5 += bf_hi(v1.z); a6 += bf_lo(v1.w); a7 += bf_hi(v1.w);
            a0 += bf_lo(v2.x); a1 += bf_hi(v2.x); a2 += bf_lo(v2.y); a3 += bf_hi(v2.y);
            a4 += bf_lo(v2.z); a5 += bf_hi(v2.z); a6 += bf_lo(v2.w); a7 += bf_hi(v2.w);
            a0 += bf_lo(v3.x); a1 += bf_hi(v3.x); a2 += bf_lo(v3.y); a3 += bf_hi(v3.y);
            a4 += bf_lo(v3.z); a5 += bf_hi(v3.z); a6 += bf_lo(v3.w); a7 += bf_hi(v3.w);
        }
        for (; i < c; i += 4) {          // tail: up to 4 predicated steps
            if (i + quarter < c) {
                int s = srt[st + i + quarter];
                uint4 vv = *(const uint4*)(hp + (size_t)s * CH);
                a0 += bf_lo(vv.x); a1 += bf_hi(vv.x); a2 += bf_lo(vv.y); a3 += bf_hi(vv.y);
                a4 += bf_lo(vv.z); a5 += bf_hi(vv.z); a6 += bf_lo(vv.w); a7 += bf_hi(vv.w);
            }
        }
        // reduce across the 4 quarters
        a0 += __shfl_xor(a0, 16); a0 += __shfl_xor(a0, 32);
        a1 += __shfl_xor(a1, 16); a1 += __shfl_xor(a1, 32);
        a2 += __shfl_xor(a2, 16); a2 += __shfl_xor(a2, 32);
        a3 += __shfl_xor(a3, 16); a3 += __shfl_xor(a3, 32);
        a4 += __shfl_xor(a4, 16); a4 += __shfl_xor(a4, 32);
        a5 += __shfl_xor(a5, 16); a5 += __shfl_xor(a5, 32);
        a6 += __shfl_xor(a6, 16); a6 += __shfl_xor(a6, 32);
        a7 += __shfl_xor(a7, 16); a7 += __shfl_xor(a7, 32);
        const int n = b * BSZ + nl;
        if (quarter == 0 && n < N) {
            float* op = out + (size_t)n * CH + cq * 8;
            *(float4*)(op)     = make_float4(a0, a1, a2, a3);
            *(float4*)(op + 4) = make_float4(a4, a5, a6, a7);
        }
    }
}

// ---------------- fallback path ----------------
__global__ __launch_bounds__(256) void gemm_only(const float* __restrict__ x,
                                                 const float* __restrict__ W,
                                                 const float* __restrict__ bias,
                                                 ushort* __restrict__ h) {
    gemm_body(blockIdx.x, threadIdx.x, x, W, bias, h);
}

__global__ void atomic_agg(const ushort* __restrict__ h, const int* __restrict__ ei,
                           float* __restrict__ out) {
    int tid = blockIdx.x * blockDim.x + threadIdx.x;
    int e  = tid >> 5;
    int cg = (tid & 31) * 4;
    if (e < E) {
        int d = ei[e];
        int s = ei[E + e];
        ushort4 v = *(const ushort4*)(h + (size_t)s * CH + cg);
        float* o = out + (size_t)d * CH + cg;
        atomicAdd(o + 0, __uint_as_float((unsigned)v.x << 16));
        atomicAdd(o + 1, __uint_as_float((unsigned)v.y << 16));
        atomicAdd(o + 2, __uint_as_float((unsigned)v.z << 16));
        atomicAdd(o + 3, __uint_as_float((unsigned)v.w << 16));
    }
}

extern "C" void kernel_launch(void* const* d_in, const int* in_sizes, int n_in,
                              void* d_out, int out_size, void* d_ws, size_t ws_size,
                              hipStream_t stream) {
    const float* x  = (const float*)d_in[0];
    const int*   ei = (const int*)d_in[1];   // [2][E] int32: row0=dst, row1=src
    const float* W  = (const float*)d_in[2];
    const float* b  = (const float*)d_in[3];
    float* out = (float*)d_out;

    char* ws = (char*)d_ws;
    ushort* h = (ushort*)(ws + H_OFF);

    if (ws_size >= REQUIRED) {
        unsigned* pairs = (unsigned*)(ws + PAIRS_OFF);
        int*      gcur  = (int*)(ws + GCUR_OFF);

        hipMemsetAsync(gcur, 0, NB * sizeof(int), stream);   // ws re-poisoned each call
        gemm_and_scatter<<<PBLK + GEMM_BLOCKS, 256, 0, stream>>>(x, W, b, h, ei, gcur, pairs);
        agg_fused<<<NB, 512, 0, stream>>>(h, pairs, gcur, out);
    } else if (ws_size >= FB_REQUIRED) {
        gemm_only<<<GEMM_BLOCKS, 256, 0, stream>>>(x, W, b, h);
        hipMemsetAsync(out, 0, (size_t)out_size * sizeof(float), stream);
        int total = E * 32;
        atomic_agg<<<(total + 255) / 256, 256, 0, stream>>>(h, ei, out);
    }
}

// Round 11
// 178.655 us; speedup vs baseline: 1.1136x; 1.1136x over previous
//
#include <hip/hip_runtime.h>

// Problem constants
constexpr int N  = 50000;    // nodes
constexpr int E  = 1600000;  // edges
constexpr int CH = 128;      // channels

// Bucket slab parameters
constexpr int BSZ  = 64;                   // nodes per bucket
constexpr int NB   = (N + BSZ - 1) / BSZ;  // 782 buckets (10 bits)
constexpr int CAP  = 2560;                 // slab capacity (mean 2046, +11 sigma)
constexpr int PBLK = 256;                  // scatter partition blocks
constexpr int EPB  = E / PBLK;             // 6250 edges per partition block (exact)
constexpr int GEMM_BLOCKS = N / 16;        // 3125

// Workspace layout (bytes, 256-aligned)
constexpr size_t H_OFF     = 0;                        // h bf16 [N*CH]
constexpr size_t H_SZ      = (size_t)N * CH * 2;       // 12,800,000
constexpr size_t PAIRS_OFF = H_OFF + H_SZ;             // slabs [NB][CAP] u32 packed
constexpr size_t PAIRS_SZ  = (size_t)NB * CAP * 4;     // 8,007,680
constexpr size_t GCUR_OFF  = PAIRS_OFF + PAIRS_SZ;     // bump cursors [NB] i32
constexpr size_t GCUR_SZ   = 3328;
constexpr size_t REQUIRED  = GCUR_OFF + GCUR_SZ;       // ~20.8 MB
constexpr size_t FB_REQUIRED = H_SZ;                   // fallback: h only

// float -> bf16 round-to-nearest-even (finite inputs)
static __device__ __forceinline__ ushort f2bf(float f) {
    unsigned u = __float_as_uint(f);
    return (ushort)((u + 0x7fffu + ((u >> 16) & 1u)) >> 16);
}
static __device__ __forceinline__ float bf_lo(unsigned u) { return __uint_as_float(u << 16); }
static __device__ __forceinline__ float bf_hi(unsigned u) { return __uint_as_float(u & 0xffff0000u); }

typedef __attribute__((ext_vector_type(8))) short bf16x8;
typedef __attribute__((ext_vector_type(4))) float f32x4;

// ---------------- GEMM body: 16 rows x 128 cols per 256-thread block ----------------
// mfma_f32_16x16x32_bf16, verified layouts (m89/m91): A[m=lane&15][k=q*8+j],
// B[n=lane&15][k=q*8+j], D col=lane&15,row=q*4+reg. W converted in-register.
static __device__ __forceinline__ void gemm_body(int gb, int tid,
                                                 const float* __restrict__ x,
                                                 const float* __restrict__ W,
                                                 const float* __restrict__ bias,
                                                 ushort* __restrict__ h) {
    const int m    = tid & 15;
    const int q    = (tid >> 4) & 3;
    const int wave = tid >> 6;
    const int r0   = gb * 16;
    const int c0   = wave * 32;

    const float* xrow = x + (size_t)(r0 + m) * CH + q * 8;
    const float* wr0  = W + (size_t)(c0 + m) * CH + q * 8;
    const float* wr1  = wr0 + 16 * CH;

    f32x4 acc0 = {0.f, 0.f, 0.f, 0.f};
    f32x4 acc1 = {0.f, 0.f, 0.f, 0.f};

#pragma unroll
    for (int kc = 0; kc < CH; kc += 32) {
        float4 xa = *(const float4*)(xrow + kc);
        float4 xb = *(const float4*)(xrow + kc + 4);
        float4 wa0 = *(const float4*)(wr0 + kc);
        float4 wb0 = *(const float4*)(wr0 + kc + 4);
        float4 wa1 = *(const float4*)(wr1 + kc);
        float4 wb1 = *(const float4*)(wr1 + kc + 4);
        bf16x8 a, b0, b1;
        a[0] = (short)f2bf(xa.x); a[1] = (short)f2bf(xa.y);
        a[2] = (short)f2bf(xa.z); a[3] = (short)f2bf(xa.w);
        a[4] = (short)f2bf(xb.x); a[5] = (short)f2bf(xb.y);
        a[6] = (short)f2bf(xb.z); a[7] = (short)f2bf(xb.w);
        b0[0] = (short)f2bf(wa0.x); b0[1] = (short)f2bf(wa0.y);
        b0[2] = (short)f2bf(wa0.z); b0[3] = (short)f2bf(wa0.w);
        b0[4] = (short)f2bf(wb0.x); b0[5] = (short)f2bf(wb0.y);
        b0[6] = (short)f2bf(wb0.z); b0[7] = (short)f2bf(wb0.w);
        b1[0] = (short)f2bf(wa1.x); b1[1] = (short)f2bf(wa1.y);
        b1[2] = (short)f2bf(wa1.z); b1[3] = (short)f2bf(wa1.w);
        b1[4] = (short)f2bf(wb1.x); b1[5] = (short)f2bf(wb1.y);
        b1[6] = (short)f2bf(wb1.z); b1[7] = (short)f2bf(wb1.w);
        acc0 = __builtin_amdgcn_mfma_f32_16x16x32_bf16(a, b0, acc0, 0, 0, 0);
        acc1 = __builtin_amdgcn_mfma_f32_16x16x32_bf16(a, b1, acc1, 0, 0, 0);
    }

    const int col0 = c0 + m;
    const float bb0 = bias[col0];
    const float bb1 = bias[col0 + 16];
#pragma unroll
    for (int r = 0; r < 4; r++) {
        size_t row = (size_t)(r0 + q * 4 + r) * CH;
        h[row + col0]      = f2bf(acc0[r] + bb0);
        h[row + col0 + 16] = f2bf(acc1[r] + bb1);
    }
}

// ---------------- fused: sorted edge scatter (blocks 0..PBLK) | GEMM (rest) ----------------
// Scatter role (R11): full in-LDS counting sort so global slab writes are
// SEQUENTIAL per (bucket,block) run (~8 contiguous entries = 32 B) instead of
// 1.6M random 4 B stores. Flow: stage packed (bkt<<22|dstLoc<<16|src) to LDS
// -> int hist -> ONE global atomicAdd per bucket (bump reserve) -> chunked
// ladder scan (782) -> LDS sort of 16-bit local indices -> sequential copy-out
// to pairs[gpos[bkt] + (i - lstart[bkt])]. gcur must be pre-zeroed.
__global__ __launch_bounds__(256) void gemm_and_scatter(const float* __restrict__ x,
                                                        const float* __restrict__ W,
                                                        const float* __restrict__ bias,
                                                        ushort* __restrict__ h,
                                                        const int* __restrict__ ei,
                                                        int* __restrict__ gcur,
                                                        unsigned* __restrict__ pairs) {
    __shared__ unsigned raw[EPB];      // 25000 B packed edges
    __shared__ ushort   srt16[EPB];    // 12500 B sorted local indices
    __shared__ int cnt[NB];            //  3128 B
    __shared__ int lstart[NB];         //  3128 B
    __shared__ int gpos[NB];           //  3128 B
    __shared__ int cur[NB];            //  3128 B
    __shared__ int ssum[256];          //  1024 B  (total ~51 KB -> 3 blocks/CU)
    const int bid = blockIdx.x;
    const int tid = threadIdx.x;

    if (bid >= PBLK) {
        gemm_body(bid - PBLK, tid, x, W, bias, h);
        return;
    }

    const int k = bid;
    const int* dp = ei + k * EPB;
    const int* sp = ei + E + k * EPB;

    // stage + zero hist
    for (int j = tid; j < NB; j += 256) cnt[j] = 0;
    for (int i = tid; i < EPB; i += 256) {
        int d = dp[i], s = sp[i];
        raw[i] = ((unsigned)(d >> 6) << 22) | ((unsigned)(d & (BSZ - 1)) << 16) | (unsigned)s;
    }
    __syncthreads();

    // histogram (native int LDS atomics)
    for (int i = tid; i < EPB; i += 256) atomicAdd(&cnt[raw[i] >> 22], 1);
    __syncthreads();

    // global bump-reserve: one atomic per non-empty bucket
    for (int j = tid; j < NB; j += 256) {
        int c = cnt[j];
        gpos[j] = j * CAP + (c ? atomicAdd(&gcur[j], c) : 0);
    }

    // chunked exclusive scan of cnt[0..NB): thread t owns buckets [t*4, t*4+4)
    {
        const int base = tid * 4;
        int s = 0;
#pragma unroll
        for (int i = 0; i < 4; i++) { int j = base + i; if (j < NB) s += cnt[j]; }
        ssum[tid] = s;
        __syncthreads();
        for (int o = 1; o < 256; o <<= 1) {
            int u = (tid >= o) ? ssum[tid - o] : 0;
            __syncthreads();
            ssum[tid] += u;
            __syncthreads();
        }
        int run = ssum[tid] - s;
#pragma unroll
        for (int i = 0; i < 4; i++) {
            int j = base + i;
            if (j < NB) { lstart[j] = run; cur[j] = run; run += cnt[j]; }
        }
    }
    __syncthreads();

    // LDS sort: place each edge's local index at its sorted position
    for (int i = tid; i < EPB; i += 256) {
        int p = atomicAdd(&cur[raw[i] >> 22], 1);
        srt16[p] = (ushort)i;
    }
    __syncthreads();

    // sequential copy-out: consecutive i -> consecutive slab addresses per run
    for (int i = tid; i < EPB; i += 256) {
        unsigned w = raw[srt16[i]];
        int bkt = w >> 22;
        int gdst = gpos[bkt] + (i - lstart[bkt]);
        if (gdst < (bkt + 1) * CAP)          // defensive: never cross slab end
            pairs[gdst] = w;
    }
}

// ---------------- fused local-CSR build + pull aggregation (1 bucket / block) ----------------
// 8 waves. Stage the bucket slab to LDS, int-atomic hist over 64 nodes, ladder
// scan, scatter src16 into srt[] (CSR entirely in LDS). Aggregation: each wave
// owns 8 nodes; QUARTER-wave (16 lanes) per edge, lane reads uint4 = 8 bf16
// channels (16 B). One vmem instr covers 4 rows; x4 unroll => 16 rows in
// flight per wave. Reduce across quarters via shfl_xor(16|32).
__global__ __launch_bounds__(512) void agg_fused(const ushort* __restrict__ h,
                                                 const unsigned* __restrict__ pairs,
                                                 const int* __restrict__ gcur,
                                                 float* __restrict__ out) {
    __shared__ unsigned raw[CAP];        // 10240 B
    __shared__ ushort   srt[CAP];        //  5120 B
    __shared__ int hist[BSZ], offs[BSZ], cur[BSZ];
    const int b = blockIdx.x, t = threadIdx.x;
    const int cnt = min(gcur[b], CAP);
    const int wave = t >> 6;
    const int lane = t & 63;
    const int quarter = lane >> 4;       // 0..3: which edge of a 4-edge group
    const int cq      = lane & 15;       // channel octet 0..15 (8 ch each)

    const unsigned* slab = pairs + (size_t)b * CAP;
    for (int i = t; i < cnt; i += 512) raw[i] = slab[i];
    if (t < BSZ) hist[t] = 0;
    __syncthreads();
    for (int i = t; i < cnt; i += 512) atomicAdd(&hist[(raw[i] >> 16) & (BSZ - 1)], 1);
    __syncthreads();
    int v = (t < BSZ) ? hist[t] : 0;
    if (t < BSZ) offs[t] = v;
    __syncthreads();
    for (int o = 1; o < BSZ; o <<= 1) {
        int u = 0;
        if (t < BSZ && t >= o) u = offs[t - o];
        __syncthreads();
        if (t < BSZ) offs[t] += u;
        __syncthreads();
    }
    if (t < BSZ) { int excl = offs[t] - v; offs[t] = excl; cur[t] = excl; }
    __syncthreads();
    for (int i = t; i < cnt; i += 512) {
        unsigned w = raw[i];
        int p = atomicAdd(&cur[(w >> 16) & (BSZ - 1)], 1);
        srt[p] = (ushort)(w & 0xffffu);
    }
    __syncthreads();

    const ushort* hp = h + (size_t)cq * 8;   // this lane's 8 channels

#pragma unroll
    for (int j = 0; j < 8; j++) {
        const int nl = wave * 8 + j;
        const int st = offs[nl];
        const int c  = hist[nl];
        float a0 = 0.f, a1 = 0.f, a2 = 0.f, a3 = 0.f;
        float a4 = 0.f, a5 = 0.f, a6 = 0.f, a7 = 0.f;
        int i = 0;
        for (; i + 16 <= c; i += 16) {
            const int e0 = st + i + quarter;
            int s0 = srt[e0];
            int s1 = srt[e0 + 4];
            int s2 = srt[e0 + 8];
            int s3 = srt[e0 + 12];
            uint4 v0 = *(const uint4*)(hp + (size_t)s0 * CH);
            uint4 v1 = *(const uint4*)(hp + (size_t)s1 * CH);
            uint4 v2 = *(const uint4*)(hp + (size_t)s2 * CH);
            uint4 v3 = *(const uint4*)(hp + (size_t)s3 * CH);
            a0 += bf_lo(v0.x); a1 += bf_hi(v0.x); a2 += bf_lo(v0.y); a3 += bf_hi(v0.y);
            a4 += bf_lo(v0.z); a5 += bf_hi(v0.z); a6 += bf_lo(v0.w); a7 += bf_hi(v0.w);
            a0 += bf_lo(v1.x); a1 += bf_hi(v1.x); a2 += bf_lo(v1.y); a3 += bf_hi(v1.y);
            a4 += bf_lo(v1.z); a5 += bf_hi(v1.z); a6 += bf_lo(v1.w); a7 += bf_hi(v1.w);
            a0 += bf_lo(v2.x); a1 += bf_hi(v2.x); a2 += bf_lo(v2.y); a3 += bf_hi(v2.y);
            a4 += bf_lo(v2.z); a5 += bf_hi(v2.z); a6 += bf_lo(v2.w); a7 += bf_hi(v2.w);
            a0 += bf_lo(v3.x); a1 += bf_hi(v3.x); a2 += bf_lo(v3.y); a3 += bf_hi(v3.y);
            a4 += bf_lo(v3.z); a5 += bf_hi(v3.z); a6 += bf_lo(v3.w); a7 += bf_hi(v3.w);
        }
        for (; i < c; i += 4) {          // tail: up to 4 predicated steps
            if (i + quarter < c) {
                int s = srt[st + i + quarter];
                uint4 vv = *(const uint4*)(hp + (size_t)s * CH);
                a0 += bf_lo(vv.x); a1 += bf_hi(vv.x); a2 += bf_lo(vv.y); a3 += bf_hi(vv.y);
                a4 += bf_lo(vv.z); a5 += bf_hi(vv.z); a6 += bf_lo(vv.w); a7 += bf_hi(vv.w);
            }
        }
        a0 += __shfl_xor(a0, 16); a0 += __shfl_xor(a0, 32);
        a1 += __shfl_xor(a1, 16); a1 += __shfl_xor(a1, 32);
        a2 += __shfl_xor(a2, 16); a2 += __shfl_xor(a2, 32);
        a3 += __shfl_xor(a3, 16); a3 += __shfl_xor(a3, 32);
        a4 += __shfl_xor(a4, 16); a4 += __shfl_xor(a4, 32);
        a5 += __shfl_xor(a5, 16); a5 += __shfl_xor(a5, 32);
        a6 += __shfl_xor(a6, 16); a6 += __shfl_xor(a6, 32);
        a7 += __shfl_xor(a7, 16); a7 += __shfl_xor(a7, 32);
        const int n = b * BSZ + nl;
        if (quarter == 0 && n < N) {
            float* op = out + (size_t)n * CH + cq * 8;
            *(float4*)(op)     = make_float4(a0, a1, a2, a3);
            *(float4*)(op + 4) = make_float4(a4, a5, a6, a7);
        }
    }
}

// ---------------- fallback path ----------------
__global__ __launch_bounds__(256) void gemm_only(const float* __restrict__ x,
                                                 const float* __restrict__ W,
                                                 const float* __restrict__ bias,
                                                 ushort* __restrict__ h) {
    gemm_body(blockIdx.x, threadIdx.x, x, W, bias, h);
}

__global__ void atomic_agg(const ushort* __restrict__ h, const int* __restrict__ ei,
                           float* __restrict__ out) {
    int tid = blockIdx.x * blockDim.x + threadIdx.x;
    int e  = tid >> 5;
    int cg = (tid & 31) * 4;
    if (e < E) {
        int d = ei[e];
        int s = ei[E + e];
        ushort4 v = *(const ushort4*)(h + (size_t)s * CH + cg);
        float* o = out + (size_t)d * CH + cg;
        atomicAdd(o + 0, __uint_as_float((unsigned)v.x << 16));
        atomicAdd(o + 1, __uint_as_float((unsigned)v.y << 16));
        atomicAdd(o + 2, __uint_as_float((unsigned)v.z << 16));
        atomicAdd(o + 3, __uint_as_float((unsigned)v.w << 16));
    }
}

extern "C" void kernel_launch(void* const* d_in, const int* in_sizes, int n_in,
                              void* d_out, int out_size, void* d_ws, size_t ws_size,
                              hipStream_t stream) {
    const float* x  = (const float*)d_in[0];
    const int*   ei = (const int*)d_in[1];   // [2][E] int32: row0=dst, row1=src
    const float* W  = (const float*)d_in[2];
    const float* b  = (const float*)d_in[3];
    float* out = (float*)d_out;

    char* ws = (char*)d_ws;
    ushort* h = (ushort*)(ws + H_OFF);

    if (ws_size >= REQUIRED) {
        unsigned* pairs = (unsigned*)(ws + PAIRS_OFF);
        int*      gcur  = (int*)(ws + GCUR_OFF);

        hipMemsetAsync(gcur, 0, NB * sizeof(int), stream);   // ws re-poisoned each call
        gemm_and_scatter<<<PBLK + GEMM_BLOCKS, 256, 0, stream>>>(x, W, b, h, ei, gcur, pairs);
        agg_fused<<<NB, 512, 0, stream>>>(h, pairs, gcur, out);
    } else if (ws_size >= FB_REQUIRED) {
        gemm_only<<<GEMM_BLOCKS, 256, 0, stream>>>(x, W, b, h);
        hipMemsetAsync(out, 0, (size_t)out_size * sizeof(float), stream);
        int total = E * 32;
        atomic_agg<<<(total + 255) / 256, 256, 0, stream>>>(h, ei, out);
    }
}